// Round 1
// baseline (367.194 us; speedup 1.0000x reference)
//
#include <hip/hip_runtime.h>
#include <hip/hip_bf16.h>

#define NN 192
#define NBA 3
#define NH 8
#define ND 10
#define NE_ (NN*NN)          // 36864
#define OUTC 202             // 10 + 8*16 + 8*8

// ---- workspace layout (floats) ----
static const size_t OFF_FE0  = 0;                       // [8][NE] float4 -> 1179648 f
static const size_t OFF_T0   = 1179648;                 // [8][NE]       ->  294912 f
static const size_t OFF_FE1  = OFF_T0  + 294912;        // [8][NE] float2->  589824 f
static const size_t OFF_T1   = OFF_FE1 + 589824;        // [8][NE]
static const size_t OFF_XH1  = OFF_T1  + 294912;        // [192][128]
static const size_t OFF_EINF = OFF_XH1 + 24576;         // [192][192]
static const size_t OFF_PART = OFF_EINF + 36864;        // [192][8][8][5]
static const size_t OFF_F2   = OFF_PART + 61440;        // [8][192][16]
static const size_t OFF_S2   = OFF_F2   + 24576;        // [8][192]
static const size_t OFF_T2   = OFF_S2   + 1536;
static const size_t OFF_TE   = OFF_T2   + 1536;
static const size_t OFF_CS   = OFF_TE   + 1536;         // [192]
// total ~2.51M floats ~ 10.1 MB

// ---------------- K0: attr-independent edge features ----------------
__global__ __launch_bounds__(256) void k_edge(
    const float* __restrict__ E,
    const float* __restrict__ we0, const float* __restrict__ aen0,
    const float* __restrict__ we1, const float* __restrict__ aen1,
    float4* __restrict__ fe0, float* __restrict__ t0,
    float2* __restrict__ fe1, float* __restrict__ t1)
{
    __shared__ float w0s[96], a0s[32], w1s[512], a1s[16];
    int tid = threadIdx.x;
    for (int i = tid; i < 96;  i += 256) w0s[i] = we0[i];
    for (int i = tid; i < 32;  i += 256) a0s[i] = aen0[i];
    for (int i = tid; i < 512; i += 256) w1s[i] = we1[i];
    for (int i = tid; i < 16;  i += 256) a1s[i] = aen1[i];
    __syncthreads();
    int e = blockIdx.x * 256 + tid;
    float E0 = E[e], E1 = E[NE_ + e], E2 = E[2 * NE_ + e];
    float f0[32];
    #pragma unroll
    for (int h = 0; h < 8; h++) {
        #pragma unroll
        for (int f = 0; f < 4; f++)
            f0[h*4+f] = E0*w0s[h*12+f] + E1*w0s[h*12+4+f] + E2*w0s[h*12+8+f];
        float tv = f0[h*4]*a0s[h*4] + f0[h*4+1]*a0s[h*4+1]
                 + f0[h*4+2]*a0s[h*4+2] + f0[h*4+3]*a0s[h*4+3];
        t0[h*NE_ + e] = tv;
        fe0[h*NE_ + e] = make_float4(f0[h*4], f0[h*4+1], f0[h*4+2], f0[h*4+3]);
    }
    #pragma unroll
    for (int h = 0; h < 8; h++) {
        float a = 0.f, b = 0.f;
        #pragma unroll
        for (int d = 0; d < 32; d++) {
            a += f0[d] * w1s[(h*32+d)*2];
            b += f0[d] * w1s[(h*32+d)*2+1];
        }
        fe1[h*NE_ + e] = make_float2(a, b);
        t1[h*NE_ + e]  = a*a1s[h*2] + b*a1s[h*2+1];
    }
}

// ---------------- K1: streaming e2n attention (the big one) ----------------
// block: 512 threads = 8 waves, wave h handles head h; lanes cover e.
// grid: (S=8 e-splits, 48 n-tiles of TN=4). Single-pass no-max softmax partials.
template<int DIN, int F, int FE>
__global__ __launch_bounds__(512) void k_att(
    const float* __restrict__ Xh,   // [N][DIN]
    const float* __restrict__ wn,   // [H][DIN][F]
    const float* __restrict__ aes,  // [H][F]
    const float* __restrict__ tv,   // [H][NE]
    const float* __restrict__ fev,  // [H][NE][FE]
    const float* __restrict__ adj,  // [N][NE]
    float* __restrict__ part)       // [N][S][H][FE+1]
{
    constexpr int S = 8, EPB = NE_/S, TN = 4, NW = (DIN+63)/64;
    int h = threadIdx.x >> 6;
    int lane = threadIdx.x & 63;
    int split = blockIdx.x;
    int n0 = blockIdx.y * TN;

    // s[h,n] = X_head[n,:] . wtilde[h,:],  wtilde[h,d] = sum_f wn[h,d,f]*aes[h,f]
    float wt[NW];
    #pragma unroll
    for (int i = 0; i < NW; i++) {
        int d = lane + 64*i;
        float w = 0.f;
        if (d < DIN) {
            #pragma unroll
            for (int f = 0; f < F; f++) w += wn[(h*DIN+d)*F+f] * aes[h*F+f];
        }
        wt[i] = w;
    }
    float sv[TN];
    #pragma unroll
    for (int nt = 0; nt < TN; nt++) {
        float p = 0.f;
        #pragma unroll
        for (int i = 0; i < NW; i++) {
            int d = lane + 64*i;
            if (d < DIN) p += Xh[(n0+nt)*DIN + d] * wt[i];
        }
        #pragma unroll
        for (int m = 1; m < 64; m <<= 1) p += __shfl_xor(p, m);
        sv[nt] = p;
    }

    float acc[TN][FE+1];
    #pragma unroll
    for (int nt = 0; nt < TN; nt++)
        #pragma unroll
        for (int j = 0; j <= FE; j++) acc[nt][j] = 0.f;

    const float* tp = tv + (size_t)h * NE_;
    const float* fp = fev + (size_t)h * NE_ * FE;
    int e0 = split * EPB;
    for (int e = e0 + lane; e < e0 + EPB; e += 64) {
        float t = tp[e];
        float fv[FE];
        if constexpr (FE == 4) {
            float4 q = *(const float4*)(fp + (size_t)e*4);
            fv[0]=q.x; fv[1]=q.y; fv[2]=q.z; fv[3]=q.w;
        } else {
            float2 q = *(const float2*)(fp + (size_t)e*2);
            fv[0]=q.x; fv[1]=q.y;
        }
        #pragma unroll
        for (int nt = 0; nt < TN; nt++) {
            float x = sv[nt] + t;
            float z = fmaxf(x, 0.2f*x) + adj[(size_t)(n0+nt)*NE_ + e];
            float w = __expf(z);
            acc[nt][FE] += w;
            #pragma unroll
            for (int f = 0; f < FE; f++) acc[nt][f] += w * fv[f];
        }
    }
    #pragma unroll
    for (int nt = 0; nt < TN; nt++)
        #pragma unroll
        for (int j = 0; j <= FE; j++) {
            float v = acc[nt][j];
            #pragma unroll
            for (int m = 1; m < 64; m <<= 1) v += __shfl_xor(v, m);
            acc[nt][j] = v;
        }
    if (lane == 0) {
        #pragma unroll
        for (int nt = 0; nt < TN; nt++)
            #pragma unroll
            for (int j = 0; j <= FE; j++)
                part[(((size_t)(n0+nt)*S + split)*NH + h)*(FE+1) + j] = acc[nt][j];
    }
}

// ---------------- K2: combine partials; f2, s2, t2 ----------------
template<int DIN, int F, int FE>
__global__ __launch_bounds__(256) void k_mid(
    const float* __restrict__ Xh,
    const float* __restrict__ wn,   // [H][DIN][F]
    const float* __restrict__ be,   // [H][FE]
    const float* __restrict__ wct,  // [H][F+FE][F]
    const float* __restrict__ bct,  // [H][F]
    const float* __restrict__ asf,  // [H][F]
    const float* __restrict__ anf,  // [H][F]
    const float* __restrict__ part,
    float* __restrict__ f2, float* __restrict__ s2, float* __restrict__ t2)
{
    constexpr int S = 8, DCT = F + FE;
    int n = blockIdx.x;
    int h = threadIdx.x >> 5, lane = threadIdx.x & 31;
    float v = 0.f;
    if (lane <= FE) {
        #pragma unroll
        for (int s = 0; s < S; s++)
            v += part[(((size_t)n*S + s)*NH + h)*(FE+1) + lane];
    }
    float den = __shfl(v, FE, 32);
    float nfe = (lane < FE) ? v/den + be[h*FE+lane] : 0.f;
    float fv = 0.f;
    if (lane < F) {
        for (int d = 0; d < DIN; d++) fv += Xh[n*DIN+d] * wn[(h*DIN+d)*F+lane];
    }
    __shared__ float c[NH][DCT];
    if (lane < F)  c[h][lane]     = fv;
    if (lane < FE) c[h][F + lane] = nfe;
    __syncthreads();
    float f2v = 0.f;
    if (lane < F) {
        f2v = bct[h*F+lane];
        #pragma unroll
        for (int d = 0; d < DCT; d++) f2v += c[h][d] * wct[(h*DCT+d)*F+lane];
        f2[((size_t)h*NN + n)*16 + lane] = f2v;
    }
    float s2p = (lane < F) ? f2v * asf[h*F+lane] : 0.f;
    float t2p = (lane < F) ? f2v * anf[h*F+lane] : 0.f;
    #pragma unroll
    for (int m = 1; m < 32; m <<= 1) { s2p += __shfl_xor(s2p, m); t2p += __shfl_xor(t2p, m); }
    if (lane == 0) { s2[h*NN+n] = s2p; t2[h*NN+n] = t2p; }
}

// ---------------- K3: tE[h,k] = sum_m t2[h,m]*E_info[m,k]; colsumE ----------------
__global__ __launch_bounds__(192) void k_te(
    const float* __restrict__ Einfo, const float* __restrict__ t2,
    float* __restrict__ tE, float* __restrict__ cs)
{
    int h = blockIdx.x, k = threadIdx.x;
    float a = 0.f, c = 0.f;
    for (int m = 0; m < NN; m++) {
        float ev = Einfo[m*NN + k];
        a += t2[h*NN + m] * ev;
        c += ev;
    }
    tE[h*NN + k] = a;
    if (h == 0) cs[k] = c;
}

// ---------------- K4: att2 rows, nf, outputs ----------------
template<int F, int LAYER>
__global__ __launch_bounds__(256) void k_out(
    const float* __restrict__ Aattr, // [N][N]
    const float* __restrict__ s2, const float* __restrict__ tE,
    const float* __restrict__ cs, const float* __restrict__ f2,
    const float* __restrict__ bn,   // [H][F]
    const float* __restrict__ X,
    float* __restrict__ out, int attr,
    float* __restrict__ xh1, float* __restrict__ einfo)
{
    int n = blockIdx.x;
    int h = threadIdx.x >> 5, lane = threadIdx.x & 31;
    float s2h = s2[h*NN + n];
    float z[6];
    #pragma unroll
    for (int c6 = 0; c6 < 6; c6++) {
        int k = lane + 32*c6;
        float d2v = s2h * cs[k] + tE[h*NN + k];
        z[c6] = fmaxf(d2v, 0.2f*d2v) + Aattr[n*NN + k];
    }
    float mx = z[0];
    #pragma unroll
    for (int c6 = 1; c6 < 6; c6++) mx = fmaxf(mx, z[c6]);
    #pragma unroll
    for (int m = 1; m < 32; m <<= 1) mx = fmaxf(mx, __shfl_xor(mx, m));
    float w[6], den = 0.f;
    #pragma unroll
    for (int c6 = 0; c6 < 6; c6++) { w[c6] = __expf(z[c6] - mx); den += w[c6]; }
    #pragma unroll
    for (int m = 1; m < 32; m <<= 1) den += __shfl_xor(den, m);
    __shared__ float attL[NH][NN];
    #pragma unroll
    for (int c6 = 0; c6 < 6; c6++) attL[h][lane + 32*c6] = w[c6];
    __syncthreads();
    if (lane < F) {
        float r = 0.f;
        for (int k = 0; k < NN; k++) r += attL[h][k] * f2[((size_t)h*NN + k)*16 + lane];
        r = r/den + bn[h*F + lane];
        r = r > 0.f ? r : __expf(r) - 1.f;   // elu
        out[((size_t)n*NBA + attr)*OUTC + (LAYER == 0 ? 10 : 138) + h*F + lane] = r;
        if (LAYER == 0) xh1[n*128 + h*16 + lane] = r;
    }
    if (LAYER == 0 && h == 7) {
        #pragma unroll
        for (int c6 = 0; c6 < 6; c6++) einfo[n*NN + lane + 32*c6] = w[c6] / den;
    }
    if (LAYER == 0 && h == 0 && lane < ND)
        out[((size_t)n*NBA + attr)*OUTC + lane] = X[n*ND + lane];
}

extern "C" void kernel_launch(void* const* d_in, const int* in_sizes, int n_in,
                              void* d_out, int out_size, void* d_ws, size_t ws_size,
                              hipStream_t stream) {
    const float* X    = (const float*)d_in[0];
    const float* A    = (const float*)d_in[1];
    const float* E    = (const float*)d_in[2];
    const float* adj  = (const float*)d_in[3];
    const float* w_n0 = (const float*)d_in[4];
    const float* b_n0 = (const float*)d_in[5];
    const float* as0  = (const float*)d_in[6];
    const float* an0  = (const float*)d_in[7];
    const float* w_n1 = (const float*)d_in[8];
    const float* b_n1 = (const float*)d_in[9];
    const float* as1  = (const float*)d_in[10];
    const float* an1  = (const float*)d_in[11];
    const float* w_e0 = (const float*)d_in[12];
    const float* b_e0 = (const float*)d_in[13];
    const float* w_ct0= (const float*)d_in[14];
    const float* b_ct0= (const float*)d_in[15];
    const float* aes0 = (const float*)d_in[16];
    const float* aen0 = (const float*)d_in[17];
    const float* w_e1 = (const float*)d_in[18];
    const float* b_e1 = (const float*)d_in[19];
    const float* w_ct1= (const float*)d_in[20];
    const float* b_ct1= (const float*)d_in[21];
    const float* aes1 = (const float*)d_in[22];
    const float* aen1 = (const float*)d_in[23];

    float* w    = (float*)d_ws;
    float4* fe0 = (float4*)(w + OFF_FE0);
    float*  t0  = w + OFF_T0;
    float*  fe1 = w + OFF_FE1;
    float*  t1  = w + OFF_T1;
    float*  xh1 = w + OFF_XH1;
    float*  einfo = w + OFF_EINF;
    float*  part  = w + OFF_PART;
    float*  f2  = w + OFF_F2;
    float*  s2  = w + OFF_S2;
    float*  t2  = w + OFF_T2;
    float*  tE  = w + OFF_TE;
    float*  cs  = w + OFF_CS;
    float*  out = (float*)d_out;

    k_edge<<<dim3(NE_/256), dim3(256), 0, stream>>>(E, w_e0, aen0, w_e1, aen1,
                                                    fe0, t0, (float2*)fe1, t1);

    for (int attr = 0; attr < 3; attr++) {
        // ---- layer 0 ----
        const float* wn0a = w_n0 + (size_t)attr*8*10*16;
        k_att<10,16,4><<<dim3(8,48), dim3(512), 0, stream>>>(
            X, wn0a, aes0, t0, w + OFF_FE0, adj, part);
        k_mid<10,16,4><<<dim3(NN), dim3(256), 0, stream>>>(
            X, wn0a, b_e0, w_ct0, b_ct0, as0 + attr*128, an0 + attr*128,
            part, f2, s2, t2);
        k_te<<<dim3(8), dim3(192), 0, stream>>>(E + (size_t)attr*NE_, t2, tE, cs);
        k_out<16,0><<<dim3(NN), dim3(256), 0, stream>>>(
            A + (size_t)attr*NE_, s2, tE, cs, f2, b_n0 + attr*128, X,
            out, attr, xh1, einfo);
        // ---- layer 1 ----
        const float* wn1a = w_n1 + (size_t)attr*8*128*8;
        k_att<128,8,2><<<dim3(8,48), dim3(512), 0, stream>>>(
            xh1, wn1a, aes1, t1, w + OFF_FE1, adj, part);
        k_mid<128,8,2><<<dim3(NN), dim3(256), 0, stream>>>(
            xh1, wn1a, b_e1, w_ct1, b_ct1, as1 + attr*64, an1 + attr*64,
            part, f2, s2, t2);
        k_te<<<dim3(8), dim3(192), 0, stream>>>(einfo, t2, tE, cs);
        k_out<8,1><<<dim3(NN), dim3(256), 0, stream>>>(
            A + (size_t)attr*NE_, s2, tE, cs, f2, b_n1 + attr*64, X,
            out, attr, xh1, einfo);
    }
}

// Round 2
// 169.586 us; speedup vs baseline: 2.1652x; 2.1652x over previous
//
#include <hip/hip_runtime.h>
#include <hip/hip_bf16.h>

#define NN 192
#define NBA 3
#define NH 8
#define ND 10
#define NE_ (NN*NN)          // 36864
#define OUTC 202             // 10 + 8*16 + 8*8

// ---- workspace layout (floats) ----
static const size_t OFF_FE0  = 0;                        // [8][NE] float4
static const size_t OFF_T0   = 1179648;                  // [8][NE]
static const size_t OFF_FE1  = OFF_T0  + 294912;         // [8][NE] float2
static const size_t OFF_T1   = OFF_FE1 + 589824;         // [8][NE]
static const size_t OFF_XH1  = OFF_T1  + 294912;         // [3][192][128]
static const size_t OFF_EINF = OFF_XH1 + 73728;          // [3][192][192]
static const size_t OFF_PART = OFF_EINF + 110592;        // [3][192][16][8][5]
static const size_t OFF_F2   = OFF_PART + 368640;        // [3][8][192][16]
static const size_t OFF_S2   = OFF_F2   + 73728;         // [3][8][192]
static const size_t OFF_T2   = OFF_S2   + 4608;
static const size_t OFF_TE   = OFF_T2   + 4608;
static const size_t OFF_CS   = OFF_TE   + 4608;          // [3][192]
// total ~3.0M floats ~ 12.0 MB

// ---------------- K0: attr-independent edge features ----------------
__global__ __launch_bounds__(256) void k_edge(
    const float* __restrict__ E,
    const float* __restrict__ we0, const float* __restrict__ aen0,
    const float* __restrict__ we1, const float* __restrict__ aen1,
    float4* __restrict__ fe0, float* __restrict__ t0,
    float2* __restrict__ fe1, float* __restrict__ t1)
{
    __shared__ float w0s[96], a0s[32], w1s[512], a1s[16];
    int tid = threadIdx.x;
    for (int i = tid; i < 96;  i += 256) w0s[i] = we0[i];
    for (int i = tid; i < 32;  i += 256) a0s[i] = aen0[i];
    for (int i = tid; i < 512; i += 256) w1s[i] = we1[i];
    for (int i = tid; i < 16;  i += 256) a1s[i] = aen1[i];
    __syncthreads();
    int e = blockIdx.x * 256 + tid;
    float E0 = E[e], E1 = E[NE_ + e], E2 = E[2 * NE_ + e];
    float f0[32];
    #pragma unroll
    for (int h = 0; h < 8; h++) {
        #pragma unroll
        for (int f = 0; f < 4; f++)
            f0[h*4+f] = E0*w0s[h*12+f] + E1*w0s[h*12+4+f] + E2*w0s[h*12+8+f];
        float tv = f0[h*4]*a0s[h*4] + f0[h*4+1]*a0s[h*4+1]
                 + f0[h*4+2]*a0s[h*4+2] + f0[h*4+3]*a0s[h*4+3];
        t0[h*NE_ + e] = tv;
        fe0[h*NE_ + e] = make_float4(f0[h*4], f0[h*4+1], f0[h*4+2], f0[h*4+3]);
    }
    #pragma unroll
    for (int h = 0; h < 8; h++) {
        float a = 0.f, b = 0.f;
        #pragma unroll
        for (int d = 0; d < 32; d++) {
            a += f0[d] * w1s[(h*32+d)*2];
            b += f0[d] * w1s[(h*32+d)*2+1];
        }
        fe1[h*NE_ + e] = make_float2(a, b);
        t1[h*NE_ + e]  = a*a1s[h*2] + b*a1s[h*2+1];
    }
}

// ---------------- K1: streaming e2n attention, 3 attrs fused ----------------
// block: 512 = 8 waves, wave h = head h. grid (S=16 e-splits, 64 n-tiles of TN=3).
// Single-pass no-max softmax partials (logits bounded, f32 safe).
template<int DIN, int F, int FE>
__global__ __launch_bounds__(512, 4) void k_att3(
    const float* __restrict__ Xh,   // [.][N][DIN], attr stride = xstride (0 for L0)
    int xstride,
    const float* __restrict__ wn,   // [A][H][DIN][F]
    const float* __restrict__ aes,  // [H][F]
    const float* __restrict__ tv,   // [H][NE]
    const float* __restrict__ fev,  // [H][NE][FE]
    const float* __restrict__ adj,  // [N][NE]
    float* __restrict__ part)       // [A][N][S][H][FE+1]
{
    constexpr int S = 16, EPB = NE_/S, TN = 3, NW = (DIN+63)/64;
    int h = threadIdx.x >> 6;
    int lane = threadIdx.x & 63;
    int split = blockIdx.x;
    int n0 = blockIdx.y * TN;

    // s[a,h,n] = Xh[a][n,:] . wtilde[a,h,:], wtilde = wn . aes
    float sv[NBA][TN];
    #pragma unroll
    for (int a = 0; a < NBA; a++) {
        float wt[NW];
        #pragma unroll
        for (int i = 0; i < NW; i++) {
            int d = lane + 64*i;
            float w = 0.f;
            if (d < DIN) {
                const float* wp = wn + (((size_t)a*NH + h)*DIN + d)*F;
                #pragma unroll
                for (int f = 0; f < F; f++) w += wp[f] * aes[h*F+f];
            }
            wt[i] = w;
        }
        #pragma unroll
        for (int nt = 0; nt < TN; nt++) {
            float p = 0.f;
            #pragma unroll
            for (int i = 0; i < NW; i++) {
                int d = lane + 64*i;
                if (d < DIN) p += Xh[(size_t)a*xstride + (n0+nt)*DIN + d] * wt[i];
            }
            #pragma unroll
            for (int m = 1; m < 64; m <<= 1) p += __shfl_xor(p, m);
            sv[a][nt] = p;
        }
    }

    float acc[NBA][TN][FE+1];
    #pragma unroll
    for (int a = 0; a < NBA; a++)
        #pragma unroll
        for (int nt = 0; nt < TN; nt++)
            #pragma unroll
            for (int j = 0; j <= FE; j++) acc[a][nt][j] = 0.f;

    const float* tp = tv + (size_t)h * NE_;
    const float* fp = fev + (size_t)h * NE_ * FE;
    const float* ap = adj + (size_t)n0 * NE_;
    int e0 = split * EPB;
    #pragma unroll 2
    for (int e = e0 + lane; e < e0 + EPB; e += 64) {
        float t = tp[e];
        float fv[FE];
        if constexpr (FE == 4) {
            float4 q = *(const float4*)(fp + (size_t)e*4);
            fv[0]=q.x; fv[1]=q.y; fv[2]=q.z; fv[3]=q.w;
        } else {
            float2 q = *(const float2*)(fp + (size_t)e*2);
            fv[0]=q.x; fv[1]=q.y;
        }
        float av[TN];
        #pragma unroll
        for (int nt = 0; nt < TN; nt++) av[nt] = ap[(size_t)nt*NE_ + e];
        #pragma unroll
        for (int nt = 0; nt < TN; nt++) {
            #pragma unroll
            for (int a = 0; a < NBA; a++) {
                float x = sv[a][nt] + t;
                float z = fmaxf(x, 0.2f*x) + av[nt];
                float w = __expf(z);
                acc[a][nt][FE] += w;
                #pragma unroll
                for (int f = 0; f < FE; f++) acc[a][nt][f] += w * fv[f];
            }
        }
    }
    #pragma unroll
    for (int a = 0; a < NBA; a++)
        #pragma unroll
        for (int nt = 0; nt < TN; nt++)
            #pragma unroll
            for (int j = 0; j <= FE; j++) {
                float v = acc[a][nt][j];
                #pragma unroll
                for (int m = 1; m < 64; m <<= 1) v += __shfl_xor(v, m);
                acc[a][nt][j] = v;
            }
    if (lane == 0) {
        #pragma unroll
        for (int a = 0; a < NBA; a++)
            #pragma unroll
            for (int nt = 0; nt < TN; nt++)
                #pragma unroll
                for (int j = 0; j <= FE; j++)
                    part[((((size_t)a*NN + n0+nt)*S + split)*NH + h)*(FE+1) + j] = acc[a][nt][j];
    }
}

// ---------------- K2: combine partials; f2, s2, t2 (grid.y = attr) ----------------
template<int DIN, int F, int FE>
__global__ __launch_bounds__(256) void k_mid(
    const float* __restrict__ Xh, int xstride,
    const float* __restrict__ wn,   // [A][H][DIN][F]
    const float* __restrict__ be,   // [H][FE]
    const float* __restrict__ wct,  // [H][F+FE][F]
    const float* __restrict__ bct,  // [H][F]
    const float* __restrict__ asf,  // [A][H][F]
    const float* __restrict__ anf,  // [A][H][F]
    const float* __restrict__ part, // [A][N][S][H][FE+1]
    float* __restrict__ f2, float* __restrict__ s2, float* __restrict__ t2)
{
    constexpr int S = 16, DCT = F + FE;
    int n = blockIdx.x, attr = blockIdx.y;
    int h = threadIdx.x >> 5, lane = threadIdx.x & 31;
    const float* Xp = Xh + (size_t)attr*xstride;
    const float* wnp = wn + (size_t)attr*NH*DIN*F;
    float* f2p = f2 + (size_t)attr*NH*NN*16;
    float v = 0.f;
    if (lane <= FE) {
        #pragma unroll
        for (int s = 0; s < S; s++)
            v += part[((((size_t)attr*NN + n)*S + s)*NH + h)*(FE+1) + lane];
    }
    float den = __shfl(v, FE, 32);
    float nfe = (lane < FE) ? v/den + be[h*FE+lane] : 0.f;
    float fv = 0.f;
    if (lane < F) {
        for (int d = 0; d < DIN; d++) fv += Xp[n*DIN+d] * wnp[(h*DIN+d)*F+lane];
    }
    __shared__ float c[NH][DCT];
    if (lane < F)  c[h][lane]     = fv;
    if (lane < FE) c[h][F + lane] = nfe;
    __syncthreads();
    float f2v = 0.f;
    if (lane < F) {
        f2v = bct[h*F+lane];
        #pragma unroll
        for (int d = 0; d < DCT; d++) f2v += c[h][d] * wct[(h*DCT+d)*F+lane];
        f2p[((size_t)h*NN + n)*16 + lane] = f2v;
    }
    float s2p = (lane < F) ? f2v * asf[attr*NH*F + h*F+lane] : 0.f;
    float t2p = (lane < F) ? f2v * anf[attr*NH*F + h*F+lane] : 0.f;
    #pragma unroll
    for (int m = 1; m < 32; m <<= 1) { s2p += __shfl_xor(s2p, m); t2p += __shfl_xor(t2p, m); }
    if (lane == 0) { s2[attr*NH*NN + h*NN+n] = s2p; t2[attr*NH*NN + h*NN+n] = t2p; }
}

// ---------------- K3: tE[h,k] = sum_m t2[h,m]*Einfo[m,k]; colsum (grid.y=attr) ----------------
__global__ __launch_bounds__(192) void k_te(
    const float* __restrict__ Einfo, size_t estride,
    const float* __restrict__ t2,
    float* __restrict__ tE, float* __restrict__ cs)
{
    int h = blockIdx.x, attr = blockIdx.y, k = threadIdx.x;
    const float* Ep = Einfo + (size_t)attr*estride;
    float a = 0.f, c = 0.f;
    for (int m = 0; m < NN; m++) {
        float ev = Ep[m*NN + k];
        a += t2[attr*NH*NN + h*NN + m] * ev;
        c += ev;
    }
    tE[attr*NH*NN + h*NN + k] = a;
    if (h == 0) cs[attr*NN + k] = c;
}

// ---------------- K4: att2 rows, nf, outputs (grid.y = attr) ----------------
template<int F, int LAYER>
__global__ __launch_bounds__(256) void k_out(
    const float* __restrict__ A,    // [A][N][N]
    const float* __restrict__ s2, const float* __restrict__ tE,
    const float* __restrict__ cs, const float* __restrict__ f2,
    const float* __restrict__ bn,   // [A][H][F]
    const float* __restrict__ X,
    float* __restrict__ out,
    float* __restrict__ xh1, float* __restrict__ einfo)
{
    int n = blockIdx.x, attr = blockIdx.y;
    int h = threadIdx.x >> 5, lane = threadIdx.x & 31;
    const float* Aattr = A + (size_t)attr*NE_;
    const float* f2p = f2 + (size_t)attr*NH*NN*16;
    float s2h = s2[attr*NH*NN + h*NN + n];
    float z[6];
    #pragma unroll
    for (int c6 = 0; c6 < 6; c6++) {
        int k = lane + 32*c6;
        float d2v = s2h * cs[attr*NN + k] + tE[attr*NH*NN + h*NN + k];
        z[c6] = fmaxf(d2v, 0.2f*d2v) + Aattr[n*NN + k];
    }
    float mx = z[0];
    #pragma unroll
    for (int c6 = 1; c6 < 6; c6++) mx = fmaxf(mx, z[c6]);
    #pragma unroll
    for (int m = 1; m < 32; m <<= 1) mx = fmaxf(mx, __shfl_xor(mx, m));
    float w[6], den = 0.f;
    #pragma unroll
    for (int c6 = 0; c6 < 6; c6++) { w[c6] = __expf(z[c6] - mx); den += w[c6]; }
    #pragma unroll
    for (int m = 1; m < 32; m <<= 1) den += __shfl_xor(den, m);
    __shared__ float attL[NH][NN];
    #pragma unroll
    for (int c6 = 0; c6 < 6; c6++) attL[h][lane + 32*c6] = w[c6];
    __syncthreads();
    if (lane < F) {
        float r = 0.f;
        for (int k = 0; k < NN; k++) r += attL[h][k] * f2p[((size_t)h*NN + k)*16 + lane];
        r = r/den + bn[attr*NH*F + h*F + lane];
        r = r > 0.f ? r : __expf(r) - 1.f;   // elu
        out[((size_t)n*NBA + attr)*OUTC + (LAYER == 0 ? 10 : 138) + h*F + lane] = r;
        if (LAYER == 0) xh1[(size_t)attr*NN*128 + n*128 + h*16 + lane] = r;
    }
    if (LAYER == 0 && h == 7) {
        #pragma unroll
        for (int c6 = 0; c6 < 6; c6++)
            einfo[(size_t)attr*NE_ + n*NN + lane + 32*c6] = w[c6] / den;
    }
    if (LAYER == 0 && h == 0 && lane < ND)
        out[((size_t)n*NBA + attr)*OUTC + lane] = X[n*ND + lane];
}

extern "C" void kernel_launch(void* const* d_in, const int* in_sizes, int n_in,
                              void* d_out, int out_size, void* d_ws, size_t ws_size,
                              hipStream_t stream) {
    const float* X    = (const float*)d_in[0];
    const float* A    = (const float*)d_in[1];
    const float* E    = (const float*)d_in[2];
    const float* adj  = (const float*)d_in[3];
    const float* w_n0 = (const float*)d_in[4];
    const float* b_n0 = (const float*)d_in[5];
    const float* as0  = (const float*)d_in[6];
    const float* an0  = (const float*)d_in[7];
    const float* w_n1 = (const float*)d_in[8];
    const float* b_n1 = (const float*)d_in[9];
    const float* as1  = (const float*)d_in[10];
    const float* an1  = (const float*)d_in[11];
    const float* w_e0 = (const float*)d_in[12];
    const float* b_e0 = (const float*)d_in[13];
    const float* w_ct0= (const float*)d_in[14];
    const float* b_ct0= (const float*)d_in[15];
    const float* aes0 = (const float*)d_in[16];
    const float* aen0 = (const float*)d_in[17];
    const float* w_e1 = (const float*)d_in[18];
    const float* b_e1 = (const float*)d_in[19];
    const float* w_ct1= (const float*)d_in[20];
    const float* b_ct1= (const float*)d_in[21];
    const float* aes1 = (const float*)d_in[22];
    const float* aen1 = (const float*)d_in[23];

    float* w     = (float*)d_ws;
    float4* fe0  = (float4*)(w + OFF_FE0);
    float*  t0   = w + OFF_T0;
    float*  fe1  = w + OFF_FE1;
    float*  t1   = w + OFF_T1;
    float*  xh1  = w + OFF_XH1;
    float*  einfo= w + OFF_EINF;
    float*  part = w + OFF_PART;
    float*  f2   = w + OFF_F2;
    float*  s2   = w + OFF_S2;
    float*  t2   = w + OFF_T2;
    float*  tE   = w + OFF_TE;
    float*  cs   = w + OFF_CS;
    float*  out  = (float*)d_out;

    k_edge<<<dim3(NE_/256), dim3(256), 0, stream>>>(E, w_e0, aen0, w_e1, aen1,
                                                    fe0, t0, (float2*)fe1, t1);

    // ---- layer 0 (all attrs fused in k_att3) ----
    k_att3<10,16,4><<<dim3(16,64), dim3(512), 0, stream>>>(
        X, 0, w_n0, aes0, t0, w + OFF_FE0, adj, part);
    k_mid<10,16,4><<<dim3(NN,NBA), dim3(256), 0, stream>>>(
        X, 0, w_n0, b_e0, w_ct0, b_ct0, as0, an0, part, f2, s2, t2);
    k_te<<<dim3(8,NBA), dim3(192), 0, stream>>>(E, (size_t)NE_, t2, tE, cs);
    k_out<16,0><<<dim3(NN,NBA), dim3(256), 0, stream>>>(
        A, s2, tE, cs, f2, b_n0, X, out, xh1, einfo);

    // ---- layer 1 ----
    k_att3<128,8,2><<<dim3(16,64), dim3(512), 0, stream>>>(
        xh1, NN*128, w_n1, aes1, t1, w + OFF_FE1, adj, part);
    k_mid<128,8,2><<<dim3(NN,NBA), dim3(256), 0, stream>>>(
        xh1, NN*128, w_n1, b_e1, w_ct1, b_ct1, as1, an1, part, f2, s2, t2);
    k_te<<<dim3(8,NBA), dim3(192), 0, stream>>>(einfo, (size_t)NE_, t2, tE, cs);
    k_out<8,1><<<dim3(NN,NBA), dim3(256), 0, stream>>>(
        A, s2, tE, cs, f2, b_n1, X, out, xh1, einfo);
}